// Round 3
// baseline (80.311 us; speedup 1.0000x reference)
//
#include <hip/hip_runtime.h>

typedef float f4 __attribute__((ext_vector_type(4)));

// Problem constants: N=8, D=H=W=48
constexpr int HW   = 48 * 48;            // 2304
constexpr int DHW  = 48 * 48 * 48;       // 110592
constexpr int NV   = 8 * DHW;            // 884736  voxels total
constexpr int FM   = 6 * NV;             // 5308416 face_mask elements
constexpr int FACE_CHUNK = 6 * DHW;      // 663552  faces elements per f
constexpr int FA   = 6 * FACE_CHUNK;     // 3981312 faces elements
constexpr int HW1  = 49 * 49;            // 2401
constexpr int V49  = 49 * 49 * 49;       // 117649  vertices
constexpr int VU   = 8 * V49;            // 941192  vert_used elements
constexpr int VP   = 3 * V49;            // 352947  vert_pos elements

constexpr int OFF_FA = FM;
constexpr int OFF_VU = FM + FA;
constexpr int OFF_VP = FM + FA + VU;

constexpr int T_A   = NV / 4;        // 221184: 1 thread = 4 voxels (x-quad)
constexpr int T_B   = FA / 12;       // 331776: 1 thread = 2 voxels = 12 elems
constexpr int T_C   = VU;            // 941192: 1 thread = 1 (n, vertex)
constexpr int T_D   = (VP + 3) / 4;  // 88237:  1 thread = 4 elems
constexpr int T_AB  = T_A + T_B;
constexpr int T_ABC = T_AB + T_C;
constexpr int T_TOT = T_ABC + T_D;

// Corner offsets (cz*2401 + cy*49 + cx) pre-composed with _TRI:
// OFFTAB[f*6 + t*3 + v] = off(_CORNERS[f][_TRI[t][v]])
__constant__ int OFFTAB[36] = {
    0,    1,    49,   1,    49,   50,     // f0 (z-)
    2401, 2402, 2450, 2402, 2450, 2451,   // f1 (z+)
    2401, 2402, 0,    2402, 0,    1,      // f2 (y-)
    49,   50,   2450, 50,   2450, 2451,   // f3 (y+)
    2401, 0,    2450, 0,    2450, 49,     // f4 (x-)
    1,    2402, 50,   2402, 50,   2451    // f5 (x+)
};

__device__ __forceinline__ f4 ld4(const float* p) {
  return *reinterpret_cast<const f4*>(p);
}
__device__ __forceinline__ void st4_nt(float* p, f4 v) {
  __builtin_nontemporal_store(v, reinterpret_cast<f4*>(p));
}

__global__ __launch_bounds__(256) void cubify_kernel(
    const float* __restrict__ in, float* __restrict__ out) {
  unsigned tid = blockIdx.x * 256u + threadIdx.x;

  if (tid < T_A) {
    // ---- Section A: face_mask (N,6,D,H,W), 4 voxels per thread ----
    unsigned vid0 = tid * 4u;
    unsigned n  = vid0 / DHW;
    unsigned r  = vid0 - n * DHW;
    unsigned z  = r / HW;
    unsigned r2 = r - z * HW;
    unsigned y  = r2 / 48u;
    unsigned x0 = r2 - y * 48u;          // multiple of 4

    const f4 zero = {0.f, 0.f, 0.f, 0.f};
    f4 c  = ld4(in + vid0);
    f4 zm = (z > 0u)  ? ld4(in + vid0 - HW)  : zero;
    f4 zp = (z < 47u) ? ld4(in + vid0 + HW)  : zero;
    f4 ym = (y > 0u)  ? ld4(in + vid0 - 48u) : zero;
    f4 yp = (y < 47u) ? ld4(in + vid0 + 48u) : zero;
    float cl = (x0 > 0u)  ? in[vid0 - 1u] : 0.f;
    float cr = (x0 < 44u) ? in[vid0 + 4u] : 0.f;
    f4 xm = {cl, c.x, c.y, c.z};
    f4 xp = {c.y, c.z, c.w, cr};

    unsigned base = n * (6u * DHW) + r;
#define FACE(nb, k)                                                     \
    {                                                                   \
      f4 m;                                                             \
      m.x = (c.x > 0.5f && !(nb.x > 0.5f)) ? 1.0f : 0.0f;               \
      m.y = (c.y > 0.5f && !(nb.y > 0.5f)) ? 1.0f : 0.0f;               \
      m.z = (c.z > 0.5f && !(nb.z > 0.5f)) ? 1.0f : 0.0f;               \
      m.w = (c.w > 0.5f && !(nb.w > 0.5f)) ? 1.0f : 0.0f;               \
      st4_nt(out + base + (k) * (unsigned)DHW, m);                      \
    }
    FACE(zm, 0u) FACE(zp, 1u) FACE(ym, 2u) FACE(yp, 3u) FACE(xm, 4u) FACE(xp, 5u)
#undef FACE

  } else if (tid < T_AB) {
    // ---- Section B: faces (6,D,H,W,2,3) — input-independent ----
    // 1 thread = 2 voxels = 12 elements = 3 float4 stores. 55296 threads/f.
    unsigned u    = tid - T_A;
    unsigned f    = u / 55296u;
    unsigned vox0 = (u - f * 55296u) * 2u;   // even -> same row as vox0+1
    unsigned z    = vox0 / HW;
    unsigned r2   = vox0 - z * HW;
    unsigned y    = r2 / 48u;
    unsigned x    = r2 - y * 48u;
    unsigned idb  = (z * 49u + y) * 49u + x;

    int o0 = OFFTAB[f * 6u + 0u], o1 = OFFTAB[f * 6u + 1u];
    int o2 = OFFTAB[f * 6u + 2u], o3 = OFFTAB[f * 6u + 3u];
    int o4 = OFFTAB[f * 6u + 4u], o5 = OFFTAB[f * 6u + 5u];

    float* dst = out + OFF_FA + u * 12u;
    f4 a, b, cc;
    a.x  = (float)(idb + o0); a.y  = (float)(idb + o1);
    a.z  = (float)(idb + o2); a.w  = (float)(idb + o3);
    b.x  = (float)(idb + o4); b.y  = (float)(idb + o5);
    b.z  = (float)(idb + 1u + o0); b.w = (float)(idb + 1u + o1);
    cc.x = (float)(idb + 1u + o2); cc.y = (float)(idb + 1u + o3);
    cc.z = (float)(idb + 1u + o4); cc.w = (float)(idb + 1u + o5);
    st4_nt(dst,     a);
    st4_nt(dst + 4, b);
    st4_nt(dst + 8, cc);

  } else if (tid < T_ABC) {
    // ---- Section C: vert_used (N, 49^3) by GATHER over the 2x2x2 block ----
    unsigned t   = tid - T_AB;
    unsigned n   = t / V49;
    unsigned g   = t - n * V49;
    unsigned vz  = g / HW1;
    unsigned rem = g - vz * HW1;
    unsigned vy  = rem / 49u;
    unsigned vx  = rem - vy * 49u;
    const float* bp = in + n * DHW;

    unsigned b = 0u;
#pragma unroll
    for (int dz = 0; dz < 2; ++dz)
#pragma unroll
      for (int dy = 0; dy < 2; ++dy)
#pragma unroll
        for (int dx = 0; dx < 2; ++dx) {
          int zz = (int)vz - 1 + dz;
          int yy = (int)vy - 1 + dy;
          int xx = (int)vx - 1 + dx;
          bool ok = ((unsigned)zz < 48u) & ((unsigned)yy < 48u) &
                    ((unsigned)xx < 48u);
          bool o = ok && (bp[(zz * 48 + yy) * 48 + xx] > 0.5f);
          b |= (o ? 1u : 0u) << (dz * 4 + dy * 2 + dx);
        }
    // corner of voxel v at vertex is exposed iff any of the 3 faces between
    // v and its axis-flipped partner within the 2x2x2 block is exposed
    unsigned bz = ((b >> 4) | (b << 4)) & 0xffu;
    unsigned by = ((b >> 2) & 0x33u) | ((b << 2) & 0xccu);
    unsigned bx = ((b >> 1) & 0x55u) | ((b << 1) & 0xaau);
    unsigned used = b & ((~bz | ~by | ~bx) & 0xffu);
    __builtin_nontemporal_store(used ? 1.0f : 0.0f, out + OFF_VU + t);

  } else if (tid < T_TOT) {
    // ---- Section D: vert_pos (49^3, 3) — input-independent, float4 ----
    unsigned u  = tid - T_ABC;
    unsigned k0 = u * 4u;
    if (k0 + 4u <= (unsigned)VP) {
      f4 v;
#pragma unroll
      for (int j = 0; j < 4; ++j) {
        unsigned k   = k0 + (unsigned)j;
        unsigned g   = k / 3u;
        unsigned a   = k - g * 3u;
        unsigned vz  = g / HW1;
        unsigned rem = g - vz * HW1;
        unsigned vy  = rem / 49u;
        unsigned vx  = rem - vy * 49u;
        unsigned cco = (a == 0u) ? vz : ((a == 1u) ? vy : vx);
        ((float*)&v)[j] = (float)cco - 0.5f;
      }
      st4_nt(out + OFF_VP + k0, v);
    } else {
      for (unsigned k = k0; k < (unsigned)VP; ++k) {
        unsigned g   = k / 3u;
        unsigned a   = k - g * 3u;
        unsigned vz  = g / HW1;
        unsigned rem = g - vz * HW1;
        unsigned vy  = rem / 49u;
        unsigned vx  = rem - vy * 49u;
        unsigned cco = (a == 0u) ? vz : ((a == 1u) ? vy : vx);
        __builtin_nontemporal_store((float)cco - 0.5f, out + OFF_VP + k);
      }
    }
  }
}

extern "C" void kernel_launch(void* const* d_in, const int* in_sizes, int n_in,
                              void* d_out, int out_size, void* d_ws,
                              size_t ws_size, hipStream_t stream) {
  const float* in = (const float*)d_in[0];
  float* out = (float*)d_out;
  constexpr int BLK = 256;
  constexpr int GRID = (T_TOT + BLK - 1) / BLK;  // 6182 blocks
  hipLaunchKernelGGL(cubify_kernel, dim3(GRID), dim3(BLK), 0, stream, in, out);
}

// Round 4
// 75.507 us; speedup vs baseline: 1.0636x; 1.0636x over previous
//
#include <hip/hip_runtime.h>

typedef float f4 __attribute__((ext_vector_type(4)));

// Problem constants: N=8, D=H=W=48
constexpr int HW   = 48 * 48;            // 2304
constexpr int DHW  = 48 * 48 * 48;       // 110592
constexpr int NV   = 8 * DHW;            // 884736  voxels total
constexpr int FM   = 6 * NV;             // 5308416 face_mask elements
constexpr int FACE_CHUNK = 6 * DHW;      // 663552  faces elements per f
constexpr int FA   = 6 * FACE_CHUNK;     // 3981312 faces elements
constexpr int HW1  = 49 * 49;            // 2401
constexpr int V49  = 49 * 49 * 49;       // 117649  vertices
constexpr int VU   = 8 * V49;            // 941192  vert_used elements
constexpr int VP   = 3 * V49;            // 352947  vert_pos elements

constexpr int OFF_FA = FM;
constexpr int OFF_VU = FM + FA;
constexpr int OFF_VP = FM + FA + VU;

constexpr int T_A   = NV / 4;        // 221184: 1 thread = 4 voxels (x-quad)
constexpr int T_B   = FA / 12;       // 331776: 1 thread = 2 voxels = 12 elems
constexpr int T_C   = VU;            // 941192: 1 thread = 1 (n, vertex)
constexpr int T_D   = (VP + 3) / 4;  // 88237:  1 thread = 4 elems
constexpr int T_AB  = T_A + T_B;
constexpr int T_ABC = T_AB + T_C;
constexpr int T_TOT = T_ABC + T_D;

// Corner offsets (cz*2401 + cy*49 + cx) pre-composed with _TRI:
// OFFTAB[f*6 + t*3 + v] = off(_CORNERS[f][_TRI[t][v]])
__constant__ int OFFTAB[36] = {
    0,    1,    49,   1,    49,   50,     // f0 (z-)
    2401, 2402, 2450, 2402, 2450, 2451,   // f1 (z+)
    2401, 2402, 0,    2402, 0,    1,      // f2 (y-)
    49,   50,   2450, 50,   2450, 2451,   // f3 (y+)
    2401, 0,    2450, 0,    2450, 49,     // f4 (x-)
    1,    2402, 50,   2402, 50,   2451    // f5 (x+)
};

__device__ __forceinline__ f4 ld4(const float* p) {
  return *reinterpret_cast<const f4*>(p);
}

__global__ __launch_bounds__(256) void cubify_kernel(
    const float* __restrict__ in, float* __restrict__ out) {
  unsigned tid = blockIdx.x * 256u + threadIdx.x;

  if (tid < T_A) {
    // ---- Section A: face_mask (N,6,D,H,W), 4 voxels per thread ----
    unsigned vid0 = tid * 4u;
    unsigned n  = vid0 / DHW;
    unsigned r  = vid0 - n * DHW;
    unsigned z  = r / HW;
    unsigned r2 = r - z * HW;
    unsigned y  = r2 / 48u;
    unsigned x0 = r2 - y * 48u;          // multiple of 4

    const f4 zero = {0.f, 0.f, 0.f, 0.f};
    f4 c  = ld4(in + vid0);
    f4 zm = (z > 0u)  ? ld4(in + vid0 - HW)  : zero;
    f4 zp = (z < 47u) ? ld4(in + vid0 + HW)  : zero;
    f4 ym = (y > 0u)  ? ld4(in + vid0 - 48u) : zero;
    f4 yp = (y < 47u) ? ld4(in + vid0 + 48u) : zero;
    float cl = (x0 > 0u)  ? in[vid0 - 1u] : 0.f;
    float cr = (x0 < 44u) ? in[vid0 + 4u] : 0.f;
    f4 xm = {cl, c.x, c.y, c.z};
    f4 xp = {c.y, c.z, c.w, cr};

    unsigned base = n * (6u * DHW) + r;
#define FACE(nb, k)                                                     \
    {                                                                   \
      f4 m;                                                             \
      m.x = (c.x > 0.5f && !(nb.x > 0.5f)) ? 1.0f : 0.0f;               \
      m.y = (c.y > 0.5f && !(nb.y > 0.5f)) ? 1.0f : 0.0f;               \
      m.z = (c.z > 0.5f && !(nb.z > 0.5f)) ? 1.0f : 0.0f;               \
      m.w = (c.w > 0.5f && !(nb.w > 0.5f)) ? 1.0f : 0.0f;               \
      *reinterpret_cast<f4*>(out + base + (k) * (unsigned)DHW) = m;     \
    }
    FACE(zm, 0u) FACE(zp, 1u) FACE(ym, 2u) FACE(yp, 3u) FACE(xm, 4u) FACE(xp, 5u)
#undef FACE

  } else if (tid < T_AB) {
    // ---- Section B: faces (6,D,H,W,2,3) — input-independent ----
    // 1 thread = 2 voxels = 12 elements = 3 float4 stores. 55296 threads/f.
    unsigned u    = tid - T_A;
    unsigned f    = u / 55296u;
    unsigned vox0 = (u - f * 55296u) * 2u;   // even -> same row as vox0+1
    unsigned z    = vox0 / HW;
    unsigned r2   = vox0 - z * HW;
    unsigned y    = r2 / 48u;
    unsigned x    = r2 - y * 48u;
    unsigned idb  = (z * 49u + y) * 49u + x;

    int o0 = OFFTAB[f * 6u + 0u], o1 = OFFTAB[f * 6u + 1u];
    int o2 = OFFTAB[f * 6u + 2u], o3 = OFFTAB[f * 6u + 3u];
    int o4 = OFFTAB[f * 6u + 4u], o5 = OFFTAB[f * 6u + 5u];

    float* dst = out + OFF_FA + u * 12u;
    f4 a, b, cc;
    a.x  = (float)(idb + o0); a.y  = (float)(idb + o1);
    a.z  = (float)(idb + o2); a.w  = (float)(idb + o3);
    b.x  = (float)(idb + o4); b.y  = (float)(idb + o5);
    b.z  = (float)(idb + 1u + o0); b.w = (float)(idb + 1u + o1);
    cc.x = (float)(idb + 1u + o2); cc.y = (float)(idb + 1u + o3);
    cc.z = (float)(idb + 1u + o4); cc.w = (float)(idb + 1u + o5);
    *reinterpret_cast<f4*>(dst)     = a;
    *reinterpret_cast<f4*>(dst + 4) = b;
    *reinterpret_cast<f4*>(dst + 8) = cc;

  } else if (tid < T_ABC) {
    // ---- Section C: vert_used (N, 49^3) by GATHER over the 2x2x2 block ----
    unsigned t   = tid - T_AB;
    unsigned n   = t / V49;
    unsigned g   = t - n * V49;
    unsigned vz  = g / HW1;
    unsigned rem = g - vz * HW1;
    unsigned vy  = rem / 49u;
    unsigned vx  = rem - vy * 49u;
    const float* bp = in + n * DHW;

    unsigned b = 0u;
#pragma unroll
    for (int dz = 0; dz < 2; ++dz)
#pragma unroll
      for (int dy = 0; dy < 2; ++dy)
#pragma unroll
        for (int dx = 0; dx < 2; ++dx) {
          int zz = (int)vz - 1 + dz;
          int yy = (int)vy - 1 + dy;
          int xx = (int)vx - 1 + dx;
          bool ok = ((unsigned)zz < 48u) & ((unsigned)yy < 48u) &
                    ((unsigned)xx < 48u);
          bool o = ok && (bp[(zz * 48 + yy) * 48 + xx] > 0.5f);
          b |= (o ? 1u : 0u) << (dz * 4 + dy * 2 + dx);
        }
    // corner of voxel v at vertex is exposed iff any of the 3 faces between
    // v and its axis-flipped partner within the 2x2x2 block is exposed
    unsigned bz = ((b >> 4) | (b << 4)) & 0xffu;
    unsigned by = ((b >> 2) & 0x33u) | ((b << 2) & 0xccu);
    unsigned bx = ((b >> 1) & 0x55u) | ((b << 1) & 0xaau);
    unsigned used = b & ((~bz | ~by | ~bx) & 0xffu);
    out[OFF_VU + t] = used ? 1.0f : 0.0f;

  } else if (tid < T_TOT) {
    // ---- Section D: vert_pos (49^3, 3) — input-independent, float4 ----
    unsigned u  = tid - T_ABC;
    unsigned k0 = u * 4u;
    if (k0 + 4u <= (unsigned)VP) {
      f4 v;
#pragma unroll
      for (int j = 0; j < 4; ++j) {
        unsigned k   = k0 + (unsigned)j;
        unsigned g   = k / 3u;
        unsigned a   = k - g * 3u;
        unsigned vz  = g / HW1;
        unsigned rem = g - vz * HW1;
        unsigned vy  = rem / 49u;
        unsigned vx  = rem - vy * 49u;
        unsigned cco = (a == 0u) ? vz : ((a == 1u) ? vy : vx);
        ((float*)&v)[j] = (float)cco - 0.5f;
      }
      *reinterpret_cast<f4*>(out + OFF_VP + k0) = v;
    } else {
      for (unsigned k = k0; k < (unsigned)VP; ++k) {
        unsigned g   = k / 3u;
        unsigned a   = k - g * 3u;
        unsigned vz  = g / HW1;
        unsigned rem = g - vz * HW1;
        unsigned vy  = rem / 49u;
        unsigned vx  = rem - vy * 49u;
        unsigned cco = (a == 0u) ? vz : ((a == 1u) ? vy : vx);
        out[OFF_VP + k] = (float)cco - 0.5f;
      }
    }
  }
}

extern "C" void kernel_launch(void* const* d_in, const int* in_sizes, int n_in,
                              void* d_out, int out_size, void* d_ws,
                              size_t ws_size, hipStream_t stream) {
  const float* in = (const float*)d_in[0];
  float* out = (float*)d_out;
  constexpr int BLK = 256;
  constexpr int GRID = (T_TOT + BLK - 1) / BLK;  // 6182 blocks
  hipLaunchKernelGGL(cubify_kernel, dim3(GRID), dim3(BLK), 0, stream, in, out);
}